// Round 9
// baseline (253.188 us; speedup 1.0000x reference)
//
#include <hip/hip_runtime.h>

// Problem constants: B=8, H=96, W=128, C=128, NS=4, with_shift=1
#define H 96
#define W 128
#define C 128
#define WSH 24
#define WSW 32
#define NTOK 768
#define SH 12
#define SW 16
#define KT 32        // keys per tile
#define NKT 24       // tiles per window (each tile = one spatial row)
// ws tile: K-frags 8KB + V-frags 8KB, chunk index == lane (conflict-free b128)
#define TILE_USH 8192                  // 16384 B
#define WS_NEED (128L * NKT * TILE_USH * 2)  // 50,331,648 bytes

typedef __attribute__((ext_vector_type(8))) short short8;
typedef __attribute__((ext_vector_type(4))) float floatx4;

union U8 { short8 s8; unsigned u[4]; };

__device__ inline unsigned short f2bf(float f) {
  union { float f; unsigned u; } un; un.f = f;
  unsigned r = un.u + 0x7FFF + ((un.u >> 16) & 1);
  return (unsigned short)(r >> 16);
}

// window token -> global spatial offset (y*W + x), folding the shift-roll
__device__ inline int tok_off(int tok, int wh, int ww) {
  int r = tok >> 5;
  int cc = tok & 31;
  int y = wh * WSH + r + SH; if (y >= H) y -= H;
  int x = ww * WSW + cc + SW; if (x >= W) x -= W;
  return y * W + x;
}

// async global->LDS, 16B per lane, LDS dst = wave-uniform base + lane*16
__device__ inline void gll16(const void* g, void* lds) {
  __builtin_amdgcn_global_load_lds(
      (const __attribute__((address_space(1))) unsigned int*)g,
      (__attribute__((address_space(3))) unsigned int*)lds, 16, 0, 0);
}

// ---------------- prep: fp32 K,V -> bf16 MFMA-fragment tiles in ws ----------
// (unchanged — passing since round 4 revision)
__global__ __launch_bounds__(256) void prep_kernel(const float* __restrict__ k,
                                                   const float* __restrict__ v,
                                                   unsigned short* __restrict__ ws) {
  __shared__ unsigned short Vlds[KT][136];
  const int bid = blockIdx.x;               // 3072 blocks
  const int xcd = bid & 7;
  const int jj = bid >> 3;                  // 0..383
  const int w = xcd * 16 + (jj & 15);       // window 0..127, on XCD w>>4
  const int kt = jj >> 4;                   // 0..23
  const int batch = w >> 4, win = w & 15;
  const int wh = win >> 2, ww = win & 3;
  int y = wh * WSH + kt + SH; if (y >= H) y -= H;

  const int t = threadIdx.x;
  const int key = t >> 3;           // 0..31
  const int j = t & 7;              // channel group of 16
  const int c0 = j * 16;
  int x = ww * WSW + key + SW; if (x >= W) x -= W;
  const long src = ((long)batch * H * W + (long)y * W + x) * C + c0;
  unsigned short* tile = ws + ((long)w * NKT + kt) * TILE_USH;

  // K: convert 16 channels -> two fragment chunks
  {
    const float* kp = k + src;
    short8 s0, s1;
#pragma unroll
    for (int i = 0; i < 2; ++i) {
      floatx4 a = *(const floatx4*)(kp + i * 8);
      floatx4 b = *(const floatx4*)(kp + i * 8 + 4);
      s0[i*4+0] = (short)f2bf(a[0]); s0[i*4+1] = (short)f2bf(a[1]);
      s0[i*4+2] = (short)f2bf(a[2]); s0[i*4+3] = (short)f2bf(a[3]);
      s1[i*4+0] = (short)f2bf(b[0]); s1[i*4+1] = (short)f2bf(b[1]);
      s1[i*4+2] = (short)f2bf(b[2]); s1[i*4+3] = (short)f2bf(b[3]);
    }
    short8 o0, o1;
    o0[0]=s0[0]; o0[1]=s0[1]; o0[2]=s0[2]; o0[3]=s0[3]; o0[4]=s1[0]; o0[5]=s1[1]; o0[6]=s1[2]; o0[7]=s1[3];
    o1[0]=s0[4]; o1[1]=s0[5]; o1[2]=s0[6]; o1[3]=s0[7]; o1[4]=s1[4]; o1[5]=s1[5]; o1[6]=s1[6]; o1[7]=s1[7];
    const int kc = j >> 1;
    const int q2 = (j & 1) * 2;
    const int half = key >> 4, keyh = key & 15;
    unsigned short* kout = tile + kc * 1024 + half * 512 + keyh * 8;
    *(short8*)(kout + (q2    ) * 128) = o0;   // chunk (q2*16+keyh)
    *(short8*)(kout + (q2 + 1) * 128) = o1;   // chunk ((q2+1)*16+keyh)
  }
  // V: convert into LDS [key][ch], u32-packed writes
  {
    const float* vp = v + src;
#pragma unroll
    for (int i = 0; i < 4; ++i) {
      floatx4 a = *(const floatx4*)(vp + i * 4);
      unsigned lo = (unsigned)f2bf(a[0]) | ((unsigned)f2bf(a[1]) << 16);
      unsigned hi = (unsigned)f2bf(a[2]) | ((unsigned)f2bf(a[3]) << 16);
      *(unsigned*)&Vlds[key][c0 + i*4]     = lo;
      *(unsigned*)&Vlds[key][c0 + i*4 + 2] = hi;
    }
  }
  __syncthreads();
  // V fragment chunks, permuted key order: pos p <-> key (p&1)*16 + (p>>1)
  {
    const int cb = t >> 5;
    const int rem = t & 31;
    const int col = rem >> 1, qh = rem & 1;
    const int ch = cb * 16 + col;
#pragma unroll
    for (int qs = 0; qs < 2; ++qs) {
      const int quad = qh * 2 + qs;
      short8 o;
#pragma unroll
      for (int i = 0; i < 8; ++i)
        o[i] = (short)Vlds[(i & 1) * 16 + quad * 4 + (i >> 1)][ch];
      *(short8*)(tile + 4096 + cb * 512 + (quad * 16 + col) * 8) = o;
    }
  }
}

// ---------------- main fused attention ---------------------------------------
// 1536 blocks x 256 threads (4 waves); wave = 16 q-rows (1 set); 12 q-blocks
// per window. KEY INSIGHT (r8): gfx950 bins occupancy by unified VGPR+AGPR
// total (waves/SIMD halve at 64/128/256); the 2-set wave was ~148 total ->
// hard 2-wave/SIMD cap, so rounds 2-8 never actually got >2 waves/SIMD.
// 1-set wave: oacc 32 AGPR + qfrag 16 + kf/vf 64 transient + misc ~ <=128
// total under __launch_bounds__(256,4) -> 4 waves/SIMD for real. LDS cut to
// DOUBLE buffer (32 KB) so 4 blocks/CU fit (4x32=128 <=160 KB).
// 2-barrier/iter schedule keeps staging race-free with only 2 buffers:
//   [ds_read all K,V of t] lgkm(0)+barrier   (all waves done reading buf)
//   [stage(t+2) into buf]  (just freed)
//   [QK -> softmax -> PV]  (covers stage latency)
//   [vmcnt(4)+barrier]     (stage(t+1) landed; counted, not drained)
// SWAPPED QK^T (A=kf, B=qfrag): lane (col,quad) holds P[key=quad*4+r(+16)]
// [q=col] == its own PV A-fragment under the ws V-permutation; packed dwords
// f2bf(p0)|f2bf(p1)<<16 ARE the pf fragment (r7, verified on-harness).
__global__ __launch_bounds__(256, 4) void attn_main(const float* __restrict__ q,
                                                    const unsigned short* __restrict__ ws,
                                                    float* __restrict__ out) {
  __shared__ unsigned short Kv[2][TILE_USH];       // 32 KB double-buffered

  const int bid = blockIdx.x;        // 0..1535
  const int x8 = bid & 7;
  const int i = bid >> 3;            // 0..191
  const int w = x8 * 16 + (i & 15);  // window 0..127 (XCD-matched to prep)
  const int qb = i >> 4;             // 0..11 (64 q each)
  const int batch = w >> 4, win = w & 15;
  const int wh = win >> 2, ww = win & 3;

  const int tid = threadIdx.x;
  const int wv = tid >> 6, lane = tid & 63;
  const int col = lane & 15, quad = lane >> 4;
  const long bbase = (long)batch * (H * W * C);
  const int qbase = qb * 64 + wv * 16;   // multiple of 16 (set = half spatial row)
  const int loff = lane * 8;         // fragment chunk offset (ushorts), linear

  const char* wtile = (const char*)(ws + (long)w * (NKT * TILE_USH));

  auto stage = [&](int buf, int kt) {
    const char* g = wtile + ((long)kt << 14);
#pragma unroll
    for (int c = 0; c < 4; ++c) {
      const int chunk = wv * 4 + c;
      gll16(g + chunk * 1024 + lane * 16, &Kv[buf][chunk * 512]);
    }
  };

  stage(0, 0); stage(1, 1);   // fill both buffers; Q prologue covers latency

  // ---- Q fragment: 1 set x 4 kc, kept in registers ----
  short8 qfrag[4];
  {
    const int qtok = qbase + col;
    const float* qp = q + bbase + (long)tok_off(qtok, wh, ww) * C + quad * 8;
#pragma unroll
    for (int kc = 0; kc < 4; ++kc) {
      floatx4 a = *(const floatx4*)(qp + kc * 32);
      floatx4 b = *(const floatx4*)(qp + kc * 32 + 4);
      short8 v8;
      v8[0]=(short)f2bf(a[0]); v8[1]=(short)f2bf(a[1]); v8[2]=(short)f2bf(a[2]); v8[3]=(short)f2bf(a[3]);
      v8[4]=(short)f2bf(b[0]); v8[5]=(short)f2bf(b[1]); v8[6]=(short)f2bf(b[2]); v8[7]=(short)f2bf(b[3]);
      qfrag[kc] = v8;
    }
  }

  // ---- analytic mask region (wave-uniform; set never straddles a 32-row) ----
  int qreg;
  {
    int t0 = qbase;
    int rr_s = t0 >> 5;
    int qh = (wh == 3) ? ((rr_s >= SH) ? 2 : 1) : 0;
    int qw = (ww == 3) ? ((t0 & 16) ? 2 : 1) : 0;
    qreg = qh * 3 + qw;
  }
  const int cw0 = (ww == 3) ? 1 : 0, cw1 = (ww == 3) ? 2 : 0;
  const float MNEG = -144.2695041f;  // -100*log2(e)
  const float SC2 = 0.12751739f;     // log2(e)/sqrt(128)

  floatx4 oacc[8];
#pragma unroll
  for (int cb = 0; cb < 8; ++cb) oacc[cb] = (floatx4){0.f, 0.f, 0.f, 0.f};
  float lsum = 0.f;

  // tile 0 staged & visible (tile 1's 4 loads may remain in flight)
  asm volatile("s_waitcnt vmcnt(4)" ::: "memory");
  __builtin_amdgcn_s_barrier();

  for (int kt = 0; kt < NKT; ++kt) {
    const int buf = kt & 1;

    // ---- read ALL of tile kt from LDS (chunk==lane: conflict-free) ----
    short8 kf0[4], kf1[4], vf[8];
#pragma unroll
    for (int kc = 0; kc < 4; ++kc) {
      kf0[kc] = *(const short8*)&Kv[buf][kc * 1024 + loff];
      kf1[kc] = *(const short8*)&Kv[buf][kc * 1024 + 512 + loff];
    }
#pragma unroll
    for (int cb = 0; cb < 8; ++cb)
      vf[cb] = *(const short8*)&Kv[buf][4096 + cb * 512 + loff];

    // all waves done reading this buffer -> safe to overwrite
    asm volatile("s_waitcnt lgkmcnt(0)" ::: "memory");
    __builtin_amdgcn_s_barrier();
    if (kt + 2 < NKT) stage(buf, kt + 2);

    // ---- QK^T (swapped operands) ----
    const int khb = (wh == 3) ? ((kt >= SH) ? 6 : 3) : 0;
    const int kr0 = khb + cw0, kr1 = khb + cw1;
    floatx4 A0 = (floatx4){0.f, 0.f, 0.f, 0.f};
    floatx4 A1 = (floatx4){0.f, 0.f, 0.f, 0.f};
    __builtin_amdgcn_s_setprio(1);
#pragma unroll
    for (int kc = 0; kc < 4; ++kc) {
      A0 = __builtin_amdgcn_mfma_f32_16x16x32_bf16(kf0[kc], qfrag[kc], A0, 0, 0, 0);
      A1 = __builtin_amdgcn_mfma_f32_16x16x32_bf16(kf1[kc], qfrag[kc], A1, 0, 0, 0);
    }
    __builtin_amdgcn_s_setprio(0);

    // ---- softmax -> P fragment in registers ----
    const float m0 = (qreg == kr0) ? 0.f : MNEG;
    const float m1 = (qreg == kr1) ? 0.f : MNEG;
    float ls = 0.f;
    U8 pk;
#pragma unroll
    for (int r = 0; r < 4; ++r) {
      float p0 = __builtin_amdgcn_exp2f(fmaf(A0[r], SC2, m0));
      float p1 = __builtin_amdgcn_exp2f(fmaf(A1[r], SC2, m1));
      ls += p0 + p1;
      pk.u[r] = (unsigned)f2bf(p0) | ((unsigned)f2bf(p1) << 16);
    }
    lsum += ls;

    // ---- PV (covers the stage latency together with QK/softmax above) ----
    __builtin_amdgcn_s_setprio(1);
#pragma unroll
    for (int cb = 0; cb < 8; ++cb)
      oacc[cb] = __builtin_amdgcn_mfma_f32_16x16x32_bf16(pk.s8, vf[cb], oacc[cb], 0, 0, 0);
    __builtin_amdgcn_s_setprio(0);

    // ---- bottom: stage(kt+1) landed everywhere; counted, never drained ----
    if (kt + 1 < NKT) {
      if (kt + 2 < NKT) asm volatile("s_waitcnt vmcnt(4)" ::: "memory");
      else              asm volatile("s_waitcnt vmcnt(0)" ::: "memory");
      __builtin_amdgcn_s_barrier();
    }
  }

  // ---- epilogue: reduce l across quads, broadcast, divide, store ----
  {
    float l = lsum;
    l += __shfl_xor(l, 16);
    l += __shfl_xor(l, 32);   // full sum for q-token qbase+col (uniform over quads)
#pragma unroll
    for (int r = 0; r < 4; ++r) {
      float lr = __shfl(l, quad * 4 + r);   // l of q-token qbase+quad*4+r
      float inv = 1.0f / lr;
      int tok = qbase + quad * 4 + r;
      float* op = out + bbase + (long)tok_off(tok, wh, ww) * C + col;
#pragma unroll
      for (int cb = 0; cb < 8; ++cb) op[cb * 16] = oacc[cb][r] * inv;
    }
  }
}

// ---------------- fallback (self-contained, used only if ws too small) -------
#define KSTRF 136
#define VSTRF 40
#define PSTRF 40
__global__ __launch_bounds__(256, 2) void attn_fallback(
    const float* __restrict__ q, const float* __restrict__ k,
    const float* __restrict__ v, const float* __restrict__ mask,
    float* __restrict__ out) {
  __shared__ unsigned short Ks[KT * KSTRF];
  __shared__ unsigned short Vtl[C * VSTRF];
  __shared__ unsigned short Psf[4][16 * PSTRF];
  const int qtile = blockIdx.x;
  const int beta  = blockIdx.y;
  const int batch = beta >> 4;
  const int win   = beta & 15;
  const int wh = win >> 2, ww = win & 3;
  const int tid = threadIdx.x;
  const int wave = tid >> 6, lane = tid & 63;
  const int col = lane & 15, quad = lane >> 4;
  const long bbase = (long)batch * (H * W * C);
  const int qtok = qtile * 64 + wave * 16 + col;
  const float* qp = q + bbase + (long)tok_off(qtok, wh, ww) * C + quad * 8;
  short8 qfrag[4];
#pragma unroll
  for (int kc = 0; kc < 4; ++kc) {
    floatx4 a = *(const floatx4*)(qp + kc * 32);
    floatx4 b = *(const floatx4*)(qp + kc * 32 + 4);
    short8 s;
    s[0]=f2bf(a[0]); s[1]=f2bf(a[1]); s[2]=f2bf(a[2]); s[3]=f2bf(a[3]);
    s[4]=f2bf(b[0]); s[5]=f2bf(b[1]); s[6]=f2bf(b[2]); s[7]=f2bf(b[3]);
    qfrag[kc] = s;
  }
  floatx4 oacc[8];
#pragma unroll
  for (int i = 0; i < 8; ++i) oacc[i] = (floatx4){0.f,0.f,0.f,0.f};
  float mrow[4], lrow[4];
#pragma unroll
  for (int r = 0; r < 4; ++r) { mrow[r] = -1e30f; lrow[r] = 0.f; }
  const int skey = tid >> 3;
  const int sch  = (tid & 7) * 4;
  const float invscale = 0.088388347648318447f;
  const float* maskw = mask + (long)win * (NTOK * NTOK);
  const int qrow_m = qtile * 64 + wave * 16 + quad * 4;
  for (int kt = 0; kt < NKT; ++kt) {
    const int ktok0 = kt * KT;
    const long srow = bbase + (long)tok_off(ktok0 + skey, wh, ww) * C;
    const float* kp = k + srow;
    const float* vp = v + srow;
    __syncthreads();
#pragma unroll
    for (int j = 0; j < 4; ++j) {
      floatx4 f = *(const floatx4*)(kp + sch + j * 32);
      unsigned lo = (unsigned)f2bf(f[0]) | ((unsigned)f2bf(f[1]) << 16);
      unsigned hi = (unsigned)f2bf(f[2]) | ((unsigned)f2bf(f[3]) << 16);
      *(uint2*)&Ks[skey * KSTRF + sch + j * 32] = make_uint2(lo, hi);
    }
#pragma unroll
    for (int j = 0; j < 4; ++j) {
      floatx4 f = *(const floatx4*)(vp + sch + j * 32);
      int chb = sch + j * 32;
      Vtl[(chb + 0) * VSTRF + skey] = f2bf(f[0]);
      Vtl[(chb + 1) * VSTRF + skey] = f2bf(f[1]);
      Vtl[(chb + 2) * VSTRF + skey] = f2bf(f[2]);
      Vtl[(chb + 3) * VSTRF + skey] = f2bf(f[3]);
    }
    __syncthreads();
    floatx4 s0 = (floatx4){0.f,0.f,0.f,0.f};
    floatx4 s1 = (floatx4){0.f,0.f,0.f,0.f};
#pragma unroll
    for (int kc = 0; kc < 4; ++kc) {
      short8 k0 = *(const short8*)&Ks[col * KSTRF + kc * 32 + quad * 8];
      short8 k1 = *(const short8*)&Ks[(col + 16) * KSTRF + kc * 32 + quad * 8];
      s0 = __builtin_amdgcn_mfma_f32_16x16x32_bf16(qfrag[kc], k0, s0, 0, 0, 0);
      s1 = __builtin_amdgcn_mfma_f32_16x16x32_bf16(qfrag[kc], k1, s1, 0, 0, 0);
    }
    float mk0[4], mk1[4];
    const float* mp = maskw + (long)qrow_m * NTOK + ktok0 + col;
#pragma unroll
    for (int r = 0; r < 4; ++r) { mk0[r] = mp[r * NTOK]; mk1[r] = mp[r * NTOK + 16]; }
#pragma unroll
    for (int r = 0; r < 4; ++r) {
      float a0 = s0[r] * invscale + mk0[r];
      float a1 = s1[r] * invscale + mk1[r];
      float mx = fmaxf(a0, a1);
      mx = fmaxf(mx, __shfl_xor(mx, 1)); mx = fmaxf(mx, __shfl_xor(mx, 2));
      mx = fmaxf(mx, __shfl_xor(mx, 4)); mx = fmaxf(mx, __shfl_xor(mx, 8));
      float mnew = fmaxf(mrow[r], mx);
      float alpha = __expf(mrow[r] - mnew);
      float p0 = __expf(a0 - mnew);
      float p1 = __expf(a1 - mnew);
      float rs = p0 + p1;
      rs += __shfl_xor(rs, 1); rs += __shfl_xor(rs, 2);
      rs += __shfl_xor(rs, 4); rs += __shfl_xor(rs, 8);
      lrow[r] = lrow[r] * alpha + rs;
      mrow[r] = mnew;
#pragma unroll
      for (int cb = 0; cb < 8; ++cb) oacc[cb][r] *= alpha;
      Psf[wave][(quad * 4 + r) * PSTRF + col]      = f2bf(p0);
      Psf[wave][(quad * 4 + r) * PSTRF + 16 + col] = f2bf(p1);
    }
    __syncthreads();
    short8 pf = *(const short8*)&Psf[wave][col * PSTRF + quad * 8];
#pragma unroll
    for (int cb = 0; cb < 8; ++cb) {
      short8 vf = *(const short8*)&Vtl[(cb * 16 + col) * VSTRF + quad * 8];
      oacc[cb] = __builtin_amdgcn_mfma_f32_16x16x32_bf16(pf, vf, oacc[cb], 0, 0, 0);
    }
  }
#pragma unroll
  for (int r = 0; r < 4; ++r) {
    float inv_l = 1.0f / lrow[r];
    int tok = qtile * 64 + wave * 16 + quad * 4 + r;
    float* op = out + bbase + (long)tok_off(tok, wh, ww) * C + col;
#pragma unroll
    for (int cb = 0; cb < 8; ++cb) op[cb * 16] = oacc[cb][r] * inv_l;
  }
}

extern "C" void kernel_launch(void* const* d_in, const int* in_sizes, int n_in,
                              void* d_out, int out_size, void* d_ws, size_t ws_size,
                              hipStream_t stream) {
  const float* q    = (const float*)d_in[0];
  const float* k    = (const float*)d_in[1];
  const float* v    = (const float*)d_in[2];
  const float* mask = (const float*)d_in[3];
  float* out = (float*)d_out;
  if (ws_size >= (size_t)WS_NEED) {
    prep_kernel<<<128 * NKT, 256, 0, stream>>>(k, v, (unsigned short*)d_ws);
    attn_main<<<1536, 256, 0, stream>>>(q, (const unsigned short*)d_ws, out);
  } else {
    attn_fallback<<<dim3(12, 128), dim3(256), 0, stream>>>(q, k, v, mask, out);
  }
}

// Round 10
// 249.979 us; speedup vs baseline: 1.0128x; 1.0128x over previous
//
#include <hip/hip_runtime.h>

// Problem constants: B=8, H=96, W=128, C=128, NS=4, with_shift=1
#define H 96
#define W 128
#define C 128
#define WSH 24
#define WSW 32
#define NTOK 768
#define SH 12
#define SW 16
#define KT 32        // keys per tile
#define NKT 24       // tiles per window (each tile = one spatial row)
// ws tile: K-frags 8KB + V-frags 8KB, chunk index == lane (conflict-free b128)
#define TILE_USH 8192                  // 16384 B
#define WS_NEED (128L * NKT * TILE_USH * 2)  // 50,331,648 bytes

typedef __attribute__((ext_vector_type(8))) short short8;
typedef __attribute__((ext_vector_type(4))) float floatx4;

union U8 { short8 s8; unsigned u[4]; };

__device__ inline unsigned short f2bf(float f) {
  union { float f; unsigned u; } un; un.f = f;
  unsigned r = un.u + 0x7FFF + ((un.u >> 16) & 1);
  return (unsigned short)(r >> 16);
}

// window token -> global spatial offset (y*W + x), folding the shift-roll
__device__ inline int tok_off(int tok, int wh, int ww) {
  int r = tok >> 5;
  int cc = tok & 31;
  int y = wh * WSH + r + SH; if (y >= H) y -= H;
  int x = ww * WSW + cc + SW; if (x >= W) x -= W;
  return y * W + x;
}

// async global->LDS, 16B per lane, LDS dst = wave-uniform base + lane*16
__device__ inline void gll16(const void* g, void* lds) {
  __builtin_amdgcn_global_load_lds(
      (const __attribute__((address_space(1))) unsigned int*)g,
      (__attribute__((address_space(3))) unsigned int*)lds, 16, 0, 0);
}

// ---------------- prep: fp32 K,V -> bf16 MFMA-fragment tiles in ws ----------
// (unchanged — passing since round 4 revision)
__global__ __launch_bounds__(256) void prep_kernel(const float* __restrict__ k,
                                                   const float* __restrict__ v,
                                                   unsigned short* __restrict__ ws) {
  __shared__ unsigned short Vlds[KT][136];
  const int bid = blockIdx.x;               // 3072 blocks
  const int xcd = bid & 7;
  const int jj = bid >> 3;                  // 0..383
  const int w = xcd * 16 + (jj & 15);       // window 0..127, on XCD w>>4
  const int kt = jj >> 4;                   // 0..23
  const int batch = w >> 4, win = w & 15;
  const int wh = win >> 2, ww = win & 3;
  int y = wh * WSH + kt + SH; if (y >= H) y -= H;

  const int t = threadIdx.x;
  const int key = t >> 3;           // 0..31
  const int j = t & 7;              // channel group of 16
  const int c0 = j * 16;
  int x = ww * WSW + key + SW; if (x >= W) x -= W;
  const long src = ((long)batch * H * W + (long)y * W + x) * C + c0;
  unsigned short* tile = ws + ((long)w * NKT + kt) * TILE_USH;

  // K: convert 16 channels -> two fragment chunks
  {
    const float* kp = k + src;
    short8 s0, s1;
#pragma unroll
    for (int i = 0; i < 2; ++i) {
      floatx4 a = *(const floatx4*)(kp + i * 8);
      floatx4 b = *(const floatx4*)(kp + i * 8 + 4);
      s0[i*4+0] = (short)f2bf(a[0]); s0[i*4+1] = (short)f2bf(a[1]);
      s0[i*4+2] = (short)f2bf(a[2]); s0[i*4+3] = (short)f2bf(a[3]);
      s1[i*4+0] = (short)f2bf(b[0]); s1[i*4+1] = (short)f2bf(b[1]);
      s1[i*4+2] = (short)f2bf(b[2]); s1[i*4+3] = (short)f2bf(b[3]);
    }
    short8 o0, o1;
    o0[0]=s0[0]; o0[1]=s0[1]; o0[2]=s0[2]; o0[3]=s0[3]; o0[4]=s1[0]; o0[5]=s1[1]; o0[6]=s1[2]; o0[7]=s1[3];
    o1[0]=s0[4]; o1[1]=s0[5]; o1[2]=s0[6]; o1[3]=s0[7]; o1[4]=s1[4]; o1[5]=s1[5]; o1[6]=s1[6]; o1[7]=s1[7];
    const int kc = j >> 1;
    const int q2 = (j & 1) * 2;
    const int half = key >> 4, keyh = key & 15;
    unsigned short* kout = tile + kc * 1024 + half * 512 + keyh * 8;
    *(short8*)(kout + (q2    ) * 128) = o0;   // chunk (q2*16+keyh)
    *(short8*)(kout + (q2 + 1) * 128) = o1;   // chunk ((q2+1)*16+keyh)
  }
  // V: convert into LDS [key][ch], u32-packed writes
  {
    const float* vp = v + src;
#pragma unroll
    for (int i = 0; i < 4; ++i) {
      floatx4 a = *(const floatx4*)(vp + i * 4);
      unsigned lo = (unsigned)f2bf(a[0]) | ((unsigned)f2bf(a[1]) << 16);
      unsigned hi = (unsigned)f2bf(a[2]) | ((unsigned)f2bf(a[3]) << 16);
      *(unsigned*)&Vlds[key][c0 + i*4]     = lo;
      *(unsigned*)&Vlds[key][c0 + i*4 + 2] = hi;
    }
  }
  __syncthreads();
  // V fragment chunks, permuted key order: pos p <-> key (p&1)*16 + (p>>1)
  {
    const int cb = t >> 5;
    const int rem = t & 31;
    const int col = rem >> 1, qh = rem & 1;
    const int ch = cb * 16 + col;
#pragma unroll
    for (int qs = 0; qs < 2; ++qs) {
      const int quad = qh * 2 + qs;
      short8 o;
#pragma unroll
      for (int i = 0; i < 8; ++i)
        o[i] = (short)Vlds[(i & 1) * 16 + quad * 4 + (i >> 1)][ch];
      *(short8*)(tile + 4096 + cb * 512 + (quad * 16 + col) * 8) = o;
    }
  }
}

// ---------------- main fused attention ---------------------------------------
// 768 blocks x 512 threads (8 waves); wave = 16 q-rows (1 set); block = 128 q;
// 6 q-blocks per window. SYNTHESIS of r8+r9: r9 proved the 1-set register
// shape reaches real >2-wave/SIMD occupancy (unified VGPR+AGPR <=128), but its
// 12-blocks/window doubled ws HBM traffic (FETCH 78->150 MB) and regressed.
// Here: r9's wave shape + r8's 6-blocks/window traffic. 2 blocks/CU resident
// (LDS 32KB x 2 = 64 <= 160 KB; __launch_bounds__(512,4) -> 4 waves/EU =
// 16 waves/CU = 50% occupancy target).
// Double-buffered LDS, 2-barrier/iter schedule (race-free with 2 buffers):
//   [ds_read all K,V of t] lgkm(0)+barrier   (all waves done reading buf)
//   [stage(t+2) into buf]  (just freed; 2 chunks/wave)
//   [QK -> softmax -> PV]  (covers stage latency)
//   [vmcnt(2)+barrier]     (stage(t+1) landed; counted, not drained)
// SWAPPED QK^T (A=kf, B=qfrag): lane (col,quad) holds P[key=quad*4+r(+16)]
// [q=col] == its own PV A-fragment under the ws V-permutation; packed dwords
// f2bf(p0)|f2bf(p1)<<16 ARE the pf fragment (r7, verified on-harness).
__global__ __launch_bounds__(512, 4) void attn_main(const float* __restrict__ q,
                                                    const unsigned short* __restrict__ ws,
                                                    float* __restrict__ out) {
  __shared__ unsigned short Kv[2][TILE_USH];       // 32 KB double-buffered

  const int bid = blockIdx.x;        // 0..767
  const int x8 = bid & 7;
  const int i = bid >> 3;            // 0..95
  const int w = x8 * 16 + (i & 15);  // window 0..127 (XCD-matched to prep)
  const int qb = i >> 4;             // 0..5 (128 q each)
  const int batch = w >> 4, win = w & 15;
  const int wh = win >> 2, ww = win & 3;

  const int tid = threadIdx.x;
  const int wv = tid >> 6, lane = tid & 63;   // wv 0..7
  const int col = lane & 15, quad = lane >> 4;
  const long bbase = (long)batch * (H * W * C);
  const int qbase = qb * 128 + wv * 16;   // multiple of 16
  const int loff = lane * 8;         // fragment chunk offset (ushorts), linear

  const char* wtile = (const char*)(ws + (long)w * (NKT * TILE_USH));

  // stage tile kt into LDS buffer buf: 16 chunks of 1KB, 2 per wave
  auto stage = [&](int buf, int kt) {
    const char* g = wtile + ((long)kt << 14);
#pragma unroll
    for (int c = 0; c < 2; ++c) {
      const int chunk = wv * 2 + c;
      gll16(g + chunk * 1024 + lane * 16, &Kv[buf][chunk * 512]);
    }
  };

  stage(0, 0); stage(1, 1);   // fill both buffers; Q prologue covers latency

  // ---- Q fragment: 1 set x 4 kc, kept in registers ----
  short8 qfrag[4];
  {
    const int qtok = qbase + col;
    const float* qp = q + bbase + (long)tok_off(qtok, wh, ww) * C + quad * 8;
#pragma unroll
    for (int kc = 0; kc < 4; ++kc) {
      floatx4 a = *(const floatx4*)(qp + kc * 32);
      floatx4 b = *(const floatx4*)(qp + kc * 32 + 4);
      short8 v8;
      v8[0]=(short)f2bf(a[0]); v8[1]=(short)f2bf(a[1]); v8[2]=(short)f2bf(a[2]); v8[3]=(short)f2bf(a[3]);
      v8[4]=(short)f2bf(b[0]); v8[5]=(short)f2bf(b[1]); v8[6]=(short)f2bf(b[2]); v8[7]=(short)f2bf(b[3]);
      qfrag[kc] = v8;
    }
  }

  // ---- analytic mask region (wave-uniform; set never straddles a 32-row) ----
  int qreg;
  {
    int t0 = qbase;
    int rr_s = t0 >> 5;
    int qh = (wh == 3) ? ((rr_s >= SH) ? 2 : 1) : 0;
    int qw = (ww == 3) ? ((t0 & 16) ? 2 : 1) : 0;
    qreg = qh * 3 + qw;
  }
  const int cw0 = (ww == 3) ? 1 : 0, cw1 = (ww == 3) ? 2 : 0;
  const float MNEG = -144.2695041f;  // -100*log2(e)
  const float SC2 = 0.12751739f;     // log2(e)/sqrt(128)

  floatx4 oacc[8];
#pragma unroll
  for (int cb = 0; cb < 8; ++cb) oacc[cb] = (floatx4){0.f, 0.f, 0.f, 0.f};
  float lsum = 0.f;

  // tile 0 staged & visible (tile 1's 2 loads may remain in flight)
  asm volatile("s_waitcnt vmcnt(2)" ::: "memory");
  __builtin_amdgcn_s_barrier();

  for (int kt = 0; kt < NKT; ++kt) {
    const int buf = kt & 1;

    // ---- read ALL of tile kt from LDS (chunk==lane: conflict-free) ----
    short8 kf0[4], kf1[4], vf[8];
#pragma unroll
    for (int kc = 0; kc < 4; ++kc) {
      kf0[kc] = *(const short8*)&Kv[buf][kc * 1024 + loff];
      kf1[kc] = *(const short8*)&Kv[buf][kc * 1024 + 512 + loff];
    }
#pragma unroll
    for (int cb = 0; cb < 8; ++cb)
      vf[cb] = *(const short8*)&Kv[buf][4096 + cb * 512 + loff];

    // all waves done reading this buffer -> safe to overwrite
    asm volatile("s_waitcnt lgkmcnt(0)" ::: "memory");
    __builtin_amdgcn_s_barrier();
    if (kt + 2 < NKT) stage(buf, kt + 2);

    // ---- QK^T (swapped operands) ----
    const int khb = (wh == 3) ? ((kt >= SH) ? 6 : 3) : 0;
    const int kr0 = khb + cw0, kr1 = khb + cw1;
    floatx4 A0 = (floatx4){0.f, 0.f, 0.f, 0.f};
    floatx4 A1 = (floatx4){0.f, 0.f, 0.f, 0.f};
    __builtin_amdgcn_s_setprio(1);
#pragma unroll
    for (int kc = 0; kc < 4; ++kc) {
      A0 = __builtin_amdgcn_mfma_f32_16x16x32_bf16(kf0[kc], qfrag[kc], A0, 0, 0, 0);
      A1 = __builtin_amdgcn_mfma_f32_16x16x32_bf16(kf1[kc], qfrag[kc], A1, 0, 0, 0);
    }
    __builtin_amdgcn_s_setprio(0);

    // ---- softmax -> P fragment in registers ----
    const float m0 = (qreg == kr0) ? 0.f : MNEG;
    const float m1 = (qreg == kr1) ? 0.f : MNEG;
    float ls = 0.f;
    U8 pk;
#pragma unroll
    for (int r = 0; r < 4; ++r) {
      float p0 = __builtin_amdgcn_exp2f(fmaf(A0[r], SC2, m0));
      float p1 = __builtin_amdgcn_exp2f(fmaf(A1[r], SC2, m1));
      ls += p0 + p1;
      pk.u[r] = (unsigned)f2bf(p0) | ((unsigned)f2bf(p1) << 16);
    }
    lsum += ls;

    // ---- PV (covers the stage latency together with QK/softmax above) ----
    __builtin_amdgcn_s_setprio(1);
#pragma unroll
    for (int cb = 0; cb < 8; ++cb)
      oacc[cb] = __builtin_amdgcn_mfma_f32_16x16x32_bf16(pk.s8, vf[cb], oacc[cb], 0, 0, 0);
    __builtin_amdgcn_s_setprio(0);

    // ---- bottom: stage(kt+1) landed everywhere; counted, never drained ----
    if (kt + 1 < NKT) {
      if (kt + 2 < NKT) asm volatile("s_waitcnt vmcnt(2)" ::: "memory");
      else              asm volatile("s_waitcnt vmcnt(0)" ::: "memory");
      __builtin_amdgcn_s_barrier();
    }
  }

  // ---- epilogue: reduce l across quads, broadcast, divide, store ----
  {
    float l = lsum;
    l += __shfl_xor(l, 16);
    l += __shfl_xor(l, 32);   // full sum for q-token qbase+col (uniform over quads)
#pragma unroll
    for (int r = 0; r < 4; ++r) {
      float lr = __shfl(l, quad * 4 + r);   // l of q-token qbase+quad*4+r
      float inv = 1.0f / lr;
      int tok = qbase + quad * 4 + r;
      float* op = out + bbase + (long)tok_off(tok, wh, ww) * C + col;
#pragma unroll
      for (int cb = 0; cb < 8; ++cb) op[cb * 16] = oacc[cb][r] * inv;
    }
  }
}

// ---------------- fallback (self-contained, used only if ws too small) -------
#define KSTRF 136
#define VSTRF 40
#define PSTRF 40
__global__ __launch_bounds__(256, 2) void attn_fallback(
    const float* __restrict__ q, const float* __restrict__ k,
    const float* __restrict__ v, const float* __restrict__ mask,
    float* __restrict__ out) {
  __shared__ unsigned short Ks[KT * KSTRF];
  __shared__ unsigned short Vtl[C * VSTRF];
  __shared__ unsigned short Psf[4][16 * PSTRF];
  const int qtile = blockIdx.x;
  const int beta  = blockIdx.y;
  const int batch = beta >> 4;
  const int win   = beta & 15;
  const int wh = win >> 2, ww = win & 3;
  const int tid = threadIdx.x;
  const int wave = tid >> 6, lane = tid & 63;
  const int col = lane & 15, quad = lane >> 4;
  const long bbase = (long)batch * (H * W * C);
  const int qtok = qtile * 64 + wave * 16 + col;
  const float* qp = q + bbase + (long)tok_off(qtok, wh, ww) * C + quad * 8;
  short8 qfrag[4];
#pragma unroll
  for (int kc = 0; kc < 4; ++kc) {
    floatx4 a = *(const floatx4*)(qp + kc * 32);
    floatx4 b = *(const floatx4*)(qp + kc * 32 + 4);
    short8 s;
    s[0]=f2bf(a[0]); s[1]=f2bf(a[1]); s[2]=f2bf(a[2]); s[3]=f2bf(a[3]);
    s[4]=f2bf(b[0]); s[5]=f2bf(b[1]); s[6]=f2bf(b[2]); s[7]=f2bf(b[3]);
    qfrag[kc] = s;
  }
  floatx4 oacc[8];
#pragma unroll
  for (int i = 0; i < 8; ++i) oacc[i] = (floatx4){0.f,0.f,0.f,0.f};
  float mrow[4], lrow[4];
#pragma unroll
  for (int r = 0; r < 4; ++r) { mrow[r] = -1e30f; lrow[r] = 0.f; }
  const int skey = tid >> 3;
  const int sch  = (tid & 7) * 4;
  const float invscale = 0.088388347648318447f;
  const float* maskw = mask + (long)win * (NTOK * NTOK);
  const int qrow_m = qtile * 64 + wave * 16 + quad * 4;
  for (int kt = 0; kt < NKT; ++kt) {
    const int ktok0 = kt * KT;
    const long srow = bbase + (long)tok_off(ktok0 + skey, wh, ww) * C;
    const float* kp = k + srow;
    const float* vp = v + srow;
    __syncthreads();
#pragma unroll
    for (int j = 0; j < 4; ++j) {
      floatx4 f = *(const floatx4*)(kp + sch + j * 32);
      unsigned lo = (unsigned)f2bf(f[0]) | ((unsigned)f2bf(f[1]) << 16);
      unsigned hi = (unsigned)f2bf(f[2]) | ((unsigned)f2bf(f[3]) << 16);
      *(uint2*)&Ks[skey * KSTRF + sch + j * 32] = make_uint2(lo, hi);
    }
#pragma unroll
    for (int j = 0; j < 4; ++j) {
      floatx4 f = *(const floatx4*)(vp + sch + j * 32);
      int chb = sch + j * 32;
      Vtl[(chb + 0) * VSTRF + skey] = f2bf(f[0]);
      Vtl[(chb + 1) * VSTRF + skey] = f2bf(f[1]);
      Vtl[(chb + 2) * VSTRF + skey] = f2bf(f[2]);
      Vtl[(chb + 3) * VSTRF + skey] = f2bf(f[3]);
    }
    __syncthreads();
    floatx4 s0 = (floatx4){0.f,0.f,0.f,0.f};
    floatx4 s1 = (floatx4){0.f,0.f,0.f,0.f};
#pragma unroll
    for (int kc = 0; kc < 4; ++kc) {
      short8 k0 = *(const short8*)&Ks[col * KSTRF + kc * 32 + quad * 8];
      short8 k1 = *(const short8*)&Ks[(col + 16) * KSTRF + kc * 32 + quad * 8];
      s0 = __builtin_amdgcn_mfma_f32_16x16x32_bf16(qfrag[kc], k0, s0, 0, 0, 0);
      s1 = __builtin_amdgcn_mfma_f32_16x16x32_bf16(qfrag[kc], k1, s1, 0, 0, 0);
    }
    float mk0[4], mk1[4];
    const float* mp = maskw + (long)qrow_m * NTOK + ktok0 + col;
#pragma unroll
    for (int r = 0; r < 4; ++r) { mk0[r] = mp[r * NTOK]; mk1[r] = mp[r * NTOK + 16]; }
#pragma unroll
    for (int r = 0; r < 4; ++r) {
      float a0 = s0[r] * invscale + mk0[r];
      float a1 = s1[r] * invscale + mk1[r];
      float mx = fmaxf(a0, a1);
      mx = fmaxf(mx, __shfl_xor(mx, 1)); mx = fmaxf(mx, __shfl_xor(mx, 2));
      mx = fmaxf(mx, __shfl_xor(mx, 4)); mx = fmaxf(mx, __shfl_xor(mx, 8));
      float mnew = fmaxf(mrow[r], mx);
      float alpha = __expf(mrow[r] - mnew);
      float p0 = __expf(a0 - mnew);
      float p1 = __expf(a1 - mnew);
      float rs = p0 + p1;
      rs += __shfl_xor(rs, 1); rs += __shfl_xor(rs, 2);
      rs += __shfl_xor(rs, 4); rs += __shfl_xor(rs, 8);
      lrow[r] = lrow[r] * alpha + rs;
      mrow[r] = mnew;
#pragma unroll
      for (int cb = 0; cb < 8; ++cb) oacc[cb][r] *= alpha;
      Psf[wave][(quad * 4 + r) * PSTRF + col]      = f2bf(p0);
      Psf[wave][(quad * 4 + r) * PSTRF + 16 + col] = f2bf(p1);
    }
    __syncthreads();
    short8 pf = *(const short8*)&Psf[wave][col * PSTRF + quad * 8];
#pragma unroll
    for (int cb = 0; cb < 8; ++cb) {
      short8 vf = *(const short8*)&Vtl[(cb * 16 + col) * VSTRF + quad * 8];
      oacc[cb] = __builtin_amdgcn_mfma_f32_16x16x32_bf16(pf, vf, oacc[cb], 0, 0, 0);
    }
  }
#pragma unroll
  for (int r = 0; r < 4; ++r) {
    float inv_l = 1.0f / lrow[r];
    int tok = qtile * 64 + wave * 16 + quad * 4 + r;
    float* op = out + bbase + (long)tok_off(tok, wh, ww) * C + col;
#pragma unroll
    for (int cb = 0; cb < 8; ++cb) op[cb * 16] = oacc[cb][r] * inv_l;
  }
}

extern "C" void kernel_launch(void* const* d_in, const int* in_sizes, int n_in,
                              void* d_out, int out_size, void* d_ws, size_t ws_size,
                              hipStream_t stream) {
  const float* q    = (const float*)d_in[0];
  const float* k    = (const float*)d_in[1];
  const float* v    = (const float*)d_in[2];
  const float* mask = (const float*)d_in[3];
  float* out = (float*)d_out;
  if (ws_size >= (size_t)WS_NEED) {
    prep_kernel<<<128 * NKT, 256, 0, stream>>>(k, v, (unsigned short*)d_ws);
    attn_main<<<768, 512, 0, stream>>>(q, (const unsigned short*)d_ws, out);
  } else {
    attn_fallback<<<dim3(12, 128), dim3(256), 0, stream>>>(q, k, v, mask, out);
  }
}